// Round 5
// baseline (84.798 us; speedup 1.0000x reference)
//
#include <hip/hip_runtime.h>

// Dist_Conv2D_Dense: Chebyshev (L-inf) distance "conv".
// B=8, Cin=16, H=W=64, Cout=32, K=3, stride=1, edge-replicate pad.
// out[b][co][h][w] = max_{cin,kh,kw} |x[b][cin][clamp(h+kh-1)][clamp(w+kw-1)]
//                                    - wt[co][cin][kh][kw]|  + bias[co]
//
// Round-5 structure: one cout per block -> weight reads are wave-uniform ->
// scalar (SGPR) loads on the scalar pipe; no LDS, no barrier. Each thread
// computes 4 adjacent pixels: aligned float4 x-loads + float4 stores.

constexpr int Bn = 8, Cin = 16, Hn = 64, Wn = 64, Cout = 32;
constexpr int PPT = 4;            // pixels per thread (along w)
constexpr int BLOCK = 256;

__global__ __launch_bounds__(BLOCK, 4)
void dist_conv_kernel(const float* __restrict__ x,
                      const float* __restrict__ wt,
                      const float* __restrict__ bias,
                      float* __restrict__ out) {
    const int co   = blockIdx.x & (Cout - 1);     // 0..31  (uniform per block)
    const int pblk = blockIdx.x >> 5;             // 0..31

    const int p  = pblk * BLOCK + threadIdx.x;    // pixel-quad id 0..8191
    const int w0 = (p & 15) * 4;                  // 0,4,..,60 (16B aligned)
    const int h  = (p >> 4) & 63;
    const int b  = p >> 10;

    const int hm = max(h - 1, 0) * Wn;
    const int h0 = h * Wn;
    const int hp = min(h + 1, Hn - 1) * Wn;
    const int cl = max(w0 - 1, 0);                // left edge col (clamped)
    const int cr = min(w0 + 4, Wn - 1);           // right edge col (clamped)

    float acc[PPT] = {0.f, 0.f, 0.f, 0.f};

    const float* xb = x + b * (Cin * Hn * Wn);
    const float* wb = wt + co * (Cin * 9);        // uniform -> s_load

#pragma unroll
    for (int cin = 0; cin < Cin; ++cin) {
        const float* xc = xb + cin * (Hn * Wn);
        const float* wc = wb + cin * 9;

        // 6 columns per row: [cl, w0, w0+1, w0+2, w0+3, cr]
        float xr[3][6];
        {
            float4 v0 = *reinterpret_cast<const float4*>(xc + hm + w0);
            xr[0][0] = xc[hm + cl];
            xr[0][1] = v0.x; xr[0][2] = v0.y; xr[0][3] = v0.z; xr[0][4] = v0.w;
            xr[0][5] = xc[hm + cr];

            float4 v1 = *reinterpret_cast<const float4*>(xc + h0 + w0);
            xr[1][0] = xc[h0 + cl];
            xr[1][1] = v1.x; xr[1][2] = v1.y; xr[1][3] = v1.z; xr[1][4] = v1.w;
            xr[1][5] = xc[h0 + cr];

            float4 v2 = *reinterpret_cast<const float4*>(xc + hp + w0);
            xr[2][0] = xc[hp + cl];
            xr[2][1] = v2.x; xr[2][2] = v2.y; xr[2][3] = v2.z; xr[2][4] = v2.w;
            xr[2][5] = xc[hp + cr];
        }

#pragma unroll
        for (int kh = 0; kh < 3; ++kh) {
#pragma unroll
            for (int kw = 0; kw < 3; ++kw) {
                const float wv = wc[kh * 3 + kw];  // SGPR (uniform)
#pragma unroll
                for (int j = 0; j < PPT; ++j) {
                    // pixel j taps columns (w0+j-1 .. w0+j+1) -> xr[kh][j+kw]
                    acc[j] = fmaxf(acc[j], fabsf(xr[kh][j + kw] - wv));
                }
            }
        }
    }

    const float bi = bias[co];                     // uniform -> s_load
    float4 o;
    o.x = acc[0] + bi; o.y = acc[1] + bi; o.z = acc[2] + bi; o.w = acc[3] + bi;
    *reinterpret_cast<float4*>(out + b * (Cout * Hn * Wn) + co * (Hn * Wn) + h0 + w0) = o;
}

extern "C" void kernel_launch(void* const* d_in, const int* in_sizes, int n_in,
                              void* d_out, int out_size, void* d_ws, size_t ws_size,
                              hipStream_t stream) {
    const float* x    = (const float*)d_in[0];
    const float* wt   = (const float*)d_in[1];
    const float* bias = (const float*)d_in[2];
    float* out        = (float*)d_out;

    // grid: 32 couts * (8*64*64/4 quads / 256 threads) = 32*32 = 1024 blocks
    const int quads = Bn * Hn * Wn / PPT;          // 8192
    const int grid  = Cout * (quads / BLOCK);      // 1024
    dist_conv_kernel<<<grid, BLOCK, 0, stream>>>(x, wt, bias, out);
}